// Round 1
// baseline (837.278 us; speedup 1.0000x reference)
//
#include <hip/hip_runtime.h>

#define DD 128
#define LN_EPS_ 1e-5f
#define SLOPE 0.01f
#define TR 64

__global__ void k_init_deg(float* __restrict__ deg, int n) {
  int i = blockIdx.x * blockDim.x + threadIdx.x;
  if (i < n) deg[i] = 1.0f;
}

__global__ void k_degree(const int* __restrict__ ei, const float* __restrict__ ew,
                         float* __restrict__ deg, int ne) {
  int stride = gridDim.x * blockDim.x;
  for (int e = blockIdx.x * blockDim.x + threadIdx.x; e < ne; e += stride) {
    unsafeAtomicAdd(&deg[ei[ne + e]], ew[e]);
  }
}

// LayerNorm + write xn, init acc with self-loop contribution (xn * dinv^2), write dinv.
// One wave per row; lane handles 2 floats (float2).
__global__ void k_ln_init(const float* __restrict__ x, const float* __restrict__ lnw,
                          const float* __restrict__ lnb, const float* __restrict__ deg,
                          float* __restrict__ xn, float* __restrict__ acc,
                          float* __restrict__ dinv, int n) {
  int lane = threadIdx.x & 63;
  int row = blockIdx.x * 4 + (threadIdx.x >> 6);
  if (row >= n) return;
  float2 v = ((const float2*)(x + (size_t)row * DD))[lane];
  float s = v.x + v.y;
#pragma unroll
  for (int m = 32; m; m >>= 1) s += __shfl_xor(s, m, 64);
  float mu = s * 0.0078125f;
  float ex = v.x - mu, ey = v.y - mu;
  float q = ex * ex + ey * ey;
#pragma unroll
  for (int m = 32; m; m >>= 1) q += __shfl_xor(q, m, 64);
  float rstd = rsqrtf(q * 0.0078125f + LN_EPS_);
  float2 wv = ((const float2*)lnw)[lane];
  float2 bv = ((const float2*)lnb)[lane];
  float2 o = make_float2(ex * rstd * wv.x + bv.x, ey * rstd * wv.y + bv.y);
  ((float2*)(xn + (size_t)row * DD))[lane] = o;
  float dg = deg[row];
  float di = dg > 0.0f ? rsqrtf(dg) : 0.0f;
  float s2 = di * di;
  ((float2*)(acc + (size_t)row * DD))[lane] = make_float2(o.x * s2, o.y * s2);
  if (lane == 0) dinv[row] = di;
}

// One wave per edge: gather xn[row], scale by norm, atomic-scatter into acc[col].
__global__ void k_scatter(const int* __restrict__ ei, const float* __restrict__ ew,
                          const float* __restrict__ xn, const float* __restrict__ dinv,
                          float* __restrict__ acc, int ne) {
  int lane = threadIdx.x & 63;
  int wid = (blockIdx.x * blockDim.x + threadIdx.x) >> 6;
  int nw = (gridDim.x * blockDim.x) >> 6;
  for (int e = wid; e < ne; e += nw) {
    int r = ei[e], c = ei[ne + e];
    float norm = dinv[r] * ew[e] * dinv[c];
    float2 v = ((const float2*)(xn + (size_t)r * DD))[lane];
    float* dst = acc + (size_t)c * DD + lane * 2;
    unsafeAtomicAdd(dst, v.x * norm);
    unsafeAtomicAdd(dst + 1, v.y * norm);
  }
}

// out = leaky(agg @ Wg + bg) + xn @ Wl + bl.  64-row tile, 256 threads,
// per-thread 4x8 register tile, W + rows staged in LDS (pad stride 132).
__launch_bounds__(256, 1)
__global__ void k_final(const float* __restrict__ agg, const float* __restrict__ xn,
                        const float* __restrict__ Wg, const float* __restrict__ bg,
                        const float* __restrict__ Wl, const float* __restrict__ bl,
                        float* __restrict__ out, int n) {
  __shared__ float sW[DD * DD];       // 64 KB
  __shared__ float sR[TR][DD + 4];    // 33 KB, stride 132 floats (16B-aligned rows, bank-spread)
  int t = threadIdx.x;
  int cg = t & 15;   // 16 col-groups of 8 cols
  int rg = t >> 4;   // 16 row-groups of 4 rows
  int row0 = blockIdx.x * TR;

  const float* Ws[2] = {Wg, Wl};
  const float* Rs[2] = {agg, xn};
  float accs[2][4][8];

#pragma unroll
  for (int p = 0; p < 2; ++p) {
    __syncthreads();  // protect LDS reuse between passes
    {
      const float4* src = (const float4*)Ws[p];
      float4* dst = (float4*)sW;
      for (int i = t; i < DD * DD / 4; i += 256) dst[i] = src[i];
    }
    {
      const float* R = Rs[p];
      for (int i = t; i < TR * (DD / 4); i += 256) {
        int r = i >> 5;            // DD/4 == 32 chunks per row
        int c = (i & 31) << 2;
        float4 v = make_float4(0.f, 0.f, 0.f, 0.f);
        if (row0 + r < n) v = *(const float4*)(R + (size_t)(row0 + r) * DD + c);
        *(float4*)(&sR[r][c]) = v;
      }
    }
    __syncthreads();
#pragma unroll
    for (int r = 0; r < 4; ++r)
#pragma unroll
      for (int c = 0; c < 8; ++c) accs[p][r][c] = 0.f;

    for (int k0 = 0; k0 < DD; k0 += 4) {
      float4 av[4];
#pragma unroll
      for (int r = 0; r < 4; ++r) av[r] = *(const float4*)(&sR[rg * 4 + r][k0]);
#pragma unroll
      for (int kk = 0; kk < 4; ++kk) {
        const float4* wr = (const float4*)(&sW[(k0 + kk) * DD + cg * 8]);
        float4 b0 = wr[0], b1 = wr[1];
        float bb[8] = {b0.x, b0.y, b0.z, b0.w, b1.x, b1.y, b1.z, b1.w};
#pragma unroll
        for (int r = 0; r < 4; ++r) {
          float a = (kk == 0) ? av[r].x : (kk == 1) ? av[r].y : (kk == 2) ? av[r].z : av[r].w;
#pragma unroll
          for (int c = 0; c < 8; ++c) accs[p][r][c] = fmaf(a, bb[c], accs[p][r][c]);
        }
      }
    }
  }

  float bgv[8], blv[8];
#pragma unroll
  for (int c = 0; c < 8; ++c) { bgv[c] = bg[cg * 8 + c]; blv[c] = bl[cg * 8 + c]; }
#pragma unroll
  for (int r = 0; r < 4; ++r) {
    int row = row0 + rg * 4 + r;
    if (row < n) {
      float o[8];
#pragma unroll
      for (int c = 0; c < 8; ++c) {
        float g = accs[0][r][c] + bgv[c];
        g = (g >= 0.f) ? g : SLOPE * g;
        o[c] = g + accs[1][r][c] + blv[c];
      }
      float4* dst = (float4*)(out + (size_t)row * DD + cg * 8);
      dst[0] = make_float4(o[0], o[1], o[2], o[3]);
      dst[1] = make_float4(o[4], o[5], o[6], o[7]);
    }
  }
}

extern "C" void kernel_launch(void* const* d_in, const int* in_sizes, int n_in,
                              void* d_out, int out_size, void* d_ws, size_t ws_size,
                              hipStream_t stream) {
  const float* x   = (const float*)d_in[0];
  const int*   ei  = (const int*)d_in[1];   // [2, E] int32
  const float* ew  = (const float*)d_in[2];
  const float* lnw = (const float*)d_in[3];
  const float* lnb = (const float*)d_in[4];
  const float* Wg  = (const float*)d_in[5];
  const float* bg  = (const float*)d_in[6];
  const float* Wl  = (const float*)d_in[7];
  const float* bl  = (const float*)d_in[8];
  float* out = (float*)d_out;

  int n  = in_sizes[0] / DD;   // 50000
  int ne = in_sizes[1] / 2;    // 800000

  float* ws   = (float*)d_ws;
  float* xn   = ws;                          // n*128
  float* acc  = xn + (size_t)n * DD;         // n*128
  float* deg  = acc + (size_t)n * DD;        // n
  float* dinv = deg + n;                     // n

  k_init_deg<<<(n + 255) / 256, 256, 0, stream>>>(deg, n);
  k_degree<<<1024, 256, 0, stream>>>(ei, ew, deg, ne);
  k_ln_init<<<(n + 3) / 4, 256, 0, stream>>>(x, lnw, lnb, deg, xn, acc, dinv, n);
  k_scatter<<<2048, 256, 0, stream>>>(ei, ew, xn, dinv, acc, ne);
  k_final<<<(n + TR - 1) / TR, 256, 0, stream>>>(acc, xn, Wg, bg, Wl, bl, out, n);
}

// Round 2
// 281.461 us; speedup vs baseline: 2.9748x; 2.9748x over previous
//
#include <hip/hip_runtime.h>

#define DD 128
#define LN_EPS_ 1e-5f
#define SLOPE 0.01f
#define TR 64

// ---- CSR build ------------------------------------------------------------

__global__ void k_init(int* __restrict__ cnt, int* __restrict__ total, int n) {
  int i = blockIdx.x * blockDim.x + threadIdx.x;
  if (i < n) cnt[i] = 0;
  if (i == 0) *total = 0;
}

__global__ void k_count(const int* __restrict__ ei, int* __restrict__ cnt, int ne) {
  int stride = gridDim.x * blockDim.x;
  for (int e = blockIdx.x * blockDim.x + threadIdx.x; e < ne; e += stride) {
    atomicAdd(&cnt[ei[ne + e]], 1);
  }
}

// Disjoint segment bases: wave handles 256 nodes (4/lane), one atomic per wave.
__global__ void k_offsets(const int* __restrict__ cnt, int* __restrict__ base,
                          int* __restrict__ cursor, int* __restrict__ total, int n) {
  int lane = threadIdx.x & 63;
  int w = (blockIdx.x * blockDim.x + threadIdx.x) >> 6;
  int i0 = w * 256 + lane * 4;
  int4 c = make_int4(0, 0, 0, 0);
  if (i0 + 3 < n) c = *(const int4*)(cnt + i0);
  else if (i0 < n) {
    c.x = cnt[i0];
    if (i0 + 1 < n) c.y = cnt[i0 + 1];
    if (i0 + 2 < n) c.z = cnt[i0 + 2];
    if (i0 + 3 < n) c.w = cnt[i0 + 3];
  }
  int s = c.x + c.y + c.z + c.w;
  int scan = s;
#pragma unroll
  for (int m = 1; m < 64; m <<= 1) {
    int t = __shfl_up(scan, m, 64);
    if (lane >= m) scan += t;
  }
  int waveSum = __shfl(scan, 63, 64);
  int wbase = 0;
  if (lane == 63) wbase = atomicAdd(total, waveSum);
  wbase = __shfl(wbase, 63, 64);
  int ex = wbase + scan - s;  // exclusive prefix for this lane's first elem
  if (i0 < n) {
    int b0 = ex, b1 = b0 + c.x, b2 = b1 + c.y, b3 = b2 + c.z;
    base[i0] = b0; cursor[i0] = b0;
    if (i0 + 1 < n) { base[i0 + 1] = b1; cursor[i0 + 1] = b1; }
    if (i0 + 2 < n) { base[i0 + 2] = b2; cursor[i0 + 2] = b2; }
    if (i0 + 3 < n) { base[i0 + 3] = b3; cursor[i0 + 3] = b3; }
  }
}

// Bucket edges by target: srcPack[p] = (src_row, edge_weight).
__global__ void k_bucket(const int* __restrict__ ei, const float* __restrict__ ew,
                         int* __restrict__ cursor, float2* __restrict__ srcPack, int ne) {
  int stride = gridDim.x * blockDim.x;
  for (int e = blockIdx.x * blockDim.x + threadIdx.x; e < ne; e += stride) {
    int r = ei[e], c = ei[ne + e];
    int p = atomicAdd(&cursor[c], 1);
    srcPack[p] = make_float2(__int_as_float(r), ew[e]);
  }
}

// dinv[i] = rsqrt(1 + sum of incoming ew). 16 lanes per node, no atomics.
__global__ void k_deg(const float2* __restrict__ srcPack, const int* __restrict__ base,
                      const int* __restrict__ cnt, float* __restrict__ dinv, int n) {
  int lane = threadIdx.x & 63;
  int w = (blockIdx.x * blockDim.x + threadIdx.x) >> 6;
  int node = w * 4 + (lane >> 4);
  int sub = lane & 15;
  if (node >= n) return;
  int b = base[node], end = b + cnt[node];
  float s = 0.f;
  for (int e = b + sub; e < end; e += 16) s += srcPack[e].y;
#pragma unroll
  for (int m = 1; m < 16; m <<= 1) s += __shfl_xor(s, m, 64);
  if (sub == 0) dinv[node] = rsqrtf(1.0f + s);
}

// ---- LayerNorm ------------------------------------------------------------

__global__ void k_ln(const float* __restrict__ x, const float* __restrict__ lnw,
                     const float* __restrict__ lnb, float* __restrict__ xn, int n) {
  int lane = threadIdx.x & 63;
  int row = blockIdx.x * 4 + (threadIdx.x >> 6);
  if (row >= n) return;
  float2 v = ((const float2*)(x + (size_t)row * DD))[lane];
  float s = v.x + v.y;
#pragma unroll
  for (int m = 32; m; m >>= 1) s += __shfl_xor(s, m, 64);
  float mu = s * 0.0078125f;
  float ex = v.x - mu, ey = v.y - mu;
  float q = ex * ex + ey * ey;
#pragma unroll
  for (int m = 32; m; m >>= 1) q += __shfl_xor(q, m, 64);
  float rstd = rsqrtf(q * 0.0078125f + LN_EPS_);
  float2 wv = ((const float2*)lnw)[lane];
  float2 bv = ((const float2*)lnb)[lane];
  ((float2*)(xn + (size_t)row * DD))[lane] =
      make_float2(ex * rstd * wv.x + bv.x, ey * rstd * wv.y + bv.y);
}

// ---- Gather-reduce aggregation (one wave per node, no atomics) -------------

__launch_bounds__(256)
__global__ void k_gather(const float2* __restrict__ srcPack, const int* __restrict__ base,
                         const int* __restrict__ cnt, const float* __restrict__ xn,
                         const float* __restrict__ dinv, float* __restrict__ acc, int n) {
  int lane = threadIdx.x & 63;
  int i = blockIdx.x * 4 + (threadIdx.x >> 6);
  if (i >= n) return;
  const float2* xn2 = (const float2*)xn;
  float di = dinv[i];
  // self-loop: xn_i * di^2  (accumulate xn_i*di now, multiply whole sum by di at end)
  float2 s = xn2[(size_t)i * 64 + lane];
  s.x *= di; s.y *= di;
  int b = base[i], end = b + cnt[i];
  for (int e0 = b; e0 < end; e0 += 64) {
    int m = min(64, end - e0);
    float2 p = make_float2(0.f, 0.f);
    if (lane < m) p = srcPack[e0 + lane];
    int src = __float_as_int(p.x);
    float ws = dinv[src] * p.y;  // dinv[src]*ew (norm without the di factor)
    int j = 0;
    for (; j + 1 < m; j += 2) {
      int s0 = __shfl(src, j, 64), s1 = __shfl(src, j + 1, 64);
      float w0 = __shfl(ws, j, 64), w1 = __shfl(ws, j + 1, 64);
      float2 v0 = xn2[(size_t)s0 * 64 + lane];
      float2 v1 = xn2[(size_t)s1 * 64 + lane];
      s.x = fmaf(v0.x, w0, s.x); s.y = fmaf(v0.y, w0, s.y);
      s.x = fmaf(v1.x, w1, s.x); s.y = fmaf(v1.y, w1, s.y);
    }
    if (j < m) {
      int s0 = __shfl(src, j, 64);
      float w0 = __shfl(ws, j, 64);
      float2 v0 = xn2[(size_t)s0 * 64 + lane];
      s.x = fmaf(v0.x, w0, s.x); s.y = fmaf(v0.y, w0, s.y);
    }
  }
  s.x *= di; s.y *= di;
  ((float2*)acc)[(size_t)i * 64 + lane] = s;
}

// ---- Fused final: out = leaky(acc@Wg + bg) + xn@Wl + bl --------------------

__launch_bounds__(256, 1)
__global__ void k_final(const float* __restrict__ agg, const float* __restrict__ xn,
                        const float* __restrict__ Wg, const float* __restrict__ bg,
                        const float* __restrict__ Wl, const float* __restrict__ bl,
                        float* __restrict__ out, int n) {
  __shared__ float sW[DD * DD];
  __shared__ float sR[TR][DD + 4];
  int t = threadIdx.x;
  int cg = t & 15;
  int rg = t >> 4;
  int row0 = blockIdx.x * TR;

  const float* Ws[2] = {Wg, Wl};
  const float* Rs[2] = {agg, xn};
  float accs[2][4][8];

#pragma unroll
  for (int p = 0; p < 2; ++p) {
    __syncthreads();
    {
      const float4* src = (const float4*)Ws[p];
      float4* dst = (float4*)sW;
      for (int i = t; i < DD * DD / 4; i += 256) dst[i] = src[i];
    }
    {
      const float* R = Rs[p];
      for (int i = t; i < TR * (DD / 4); i += 256) {
        int r = i >> 5;
        int c = (i & 31) << 2;
        float4 v = make_float4(0.f, 0.f, 0.f, 0.f);
        if (row0 + r < n) v = *(const float4*)(R + (size_t)(row0 + r) * DD + c);
        *(float4*)(&sR[r][c]) = v;
      }
    }
    __syncthreads();
#pragma unroll
    for (int r = 0; r < 4; ++r)
#pragma unroll
      for (int c = 0; c < 8; ++c) accs[p][r][c] = 0.f;

    for (int k0 = 0; k0 < DD; k0 += 4) {
      float4 av[4];
#pragma unroll
      for (int r = 0; r < 4; ++r) av[r] = *(const float4*)(&sR[rg * 4 + r][k0]);
#pragma unroll
      for (int kk = 0; kk < 4; ++kk) {
        const float4* wr = (const float4*)(&sW[(k0 + kk) * DD + cg * 8]);
        float4 b0 = wr[0], b1 = wr[1];
        float bb[8] = {b0.x, b0.y, b0.z, b0.w, b1.x, b1.y, b1.z, b1.w};
#pragma unroll
        for (int r = 0; r < 4; ++r) {
          float a = (kk == 0) ? av[r].x : (kk == 1) ? av[r].y : (kk == 2) ? av[r].z : av[r].w;
#pragma unroll
          for (int c = 0; c < 8; ++c) accs[p][r][c] = fmaf(a, bb[c], accs[p][r][c]);
        }
      }
    }
  }

  float bgv[8], blv[8];
#pragma unroll
  for (int c = 0; c < 8; ++c) { bgv[c] = bg[cg * 8 + c]; blv[c] = bl[cg * 8 + c]; }
#pragma unroll
  for (int r = 0; r < 4; ++r) {
    int row = row0 + rg * 4 + r;
    if (row < n) {
      float o[8];
#pragma unroll
      for (int c = 0; c < 8; ++c) {
        float g = accs[0][r][c] + bgv[c];
        g = (g >= 0.f) ? g : SLOPE * g;
        o[c] = g + accs[1][r][c] + blv[c];
      }
      float4* dst = (float4*)(out + (size_t)row * DD + cg * 8);
      dst[0] = make_float4(o[0], o[1], o[2], o[3]);
      dst[1] = make_float4(o[4], o[5], o[6], o[7]);
    }
  }
}

extern "C" void kernel_launch(void* const* d_in, const int* in_sizes, int n_in,
                              void* d_out, int out_size, void* d_ws, size_t ws_size,
                              hipStream_t stream) {
  const float* x   = (const float*)d_in[0];
  const int*   ei  = (const int*)d_in[1];
  const float* ew  = (const float*)d_in[2];
  const float* lnw = (const float*)d_in[3];
  const float* lnb = (const float*)d_in[4];
  const float* Wg  = (const float*)d_in[5];
  const float* bg  = (const float*)d_in[6];
  const float* Wl  = (const float*)d_in[7];
  const float* bl  = (const float*)d_in[8];
  float* out = (float*)d_out;

  int n  = in_sizes[0] / DD;   // 50000
  int ne = in_sizes[1] / 2;    // 800000

  // workspace layout (srcPack first for 8B alignment)
  float2* srcPack = (float2*)d_ws;                    // ne float2      (6.4 MB)
  float* xn   = (float*)(srcPack + ne);               // n*128          (25.6 MB)
  float* acc  = xn + (size_t)n * DD;                  // n*128          (25.6 MB)
  float* dinv = acc + (size_t)n * DD;                 // n
  int* cnt    = (int*)(dinv + n);                     // n
  int* base   = cnt + n;                              // n
  int* cursor = base + n;                             // n
  int* total  = cursor + n;                           // 1

  int W = (n + 255) / 256;                 // waves needed in k_offsets
  int offBlocks = (W * 64 + 255) / 256;

  k_init<<<(n + 255) / 256, 256, 0, stream>>>(cnt, total, n);
  k_count<<<1024, 256, 0, stream>>>(ei, cnt, ne);
  k_offsets<<<offBlocks, 256, 0, stream>>>(cnt, base, cursor, total, n);
  k_bucket<<<1024, 256, 0, stream>>>(ei, ew, cursor, srcPack, ne);
  k_ln<<<(n + 3) / 4, 256, 0, stream>>>(x, lnw, lnb, xn, n);
  k_deg<<<(n + 15) / 16, 256, 0, stream>>>(srcPack, base, cnt, dinv, n);
  k_gather<<<(n + 3) / 4, 256, 0, stream>>>(srcPack, base, cnt, xn, dinv, acc, n);
  k_final<<<(n + TR - 1) / TR, 256, 0, stream>>>(acc, xn, Wg, bg, Wl, bl, out, n);
}

// Round 4
// 173.221 us; speedup vs baseline: 4.8336x; 1.6249x over previous
//
#include <hip/hip_runtime.h>
#include <hip/hip_bf16.h>

#define DD 128
#define LN_EPS_ 1e-5f
#define SLOPE 0.01f

typedef __attribute__((ext_vector_type(8))) short bf16x8;
typedef __attribute__((ext_vector_type(4))) float f32x4;

__device__ __forceinline__ __hip_bfloat162 pack_bf162(float a, float b) {
  __hip_bfloat162 r;
  r.x = __float2bfloat16(a);
  r.y = __float2bfloat16(b);
  return r;
}

// ---- CSR build ------------------------------------------------------------

__global__ void k_init(int* __restrict__ cnt, int* __restrict__ total, int n) {
  int i = blockIdx.x * blockDim.x + threadIdx.x;
  if (i < n) cnt[i] = 0;
  if (i == 0) *total = 0;
}

__global__ void k_count(const int* __restrict__ ei, int* __restrict__ cnt, int ne) {
  int stride = gridDim.x * blockDim.x;
  for (int e = blockIdx.x * blockDim.x + threadIdx.x; e < ne; e += stride) {
    atomicAdd(&cnt[ei[ne + e]], 1);
  }
}

__global__ void k_offsets(const int* __restrict__ cnt, int* __restrict__ base,
                          int* __restrict__ cursor, int* __restrict__ total, int n) {
  int lane = threadIdx.x & 63;
  int w = (blockIdx.x * blockDim.x + threadIdx.x) >> 6;
  int i0 = w * 256 + lane * 4;
  int4 c = make_int4(0, 0, 0, 0);
  if (i0 + 3 < n) c = *(const int4*)(cnt + i0);
  else if (i0 < n) {
    c.x = cnt[i0];
    if (i0 + 1 < n) c.y = cnt[i0 + 1];
    if (i0 + 2 < n) c.z = cnt[i0 + 2];
    if (i0 + 3 < n) c.w = cnt[i0 + 3];
  }
  int s = c.x + c.y + c.z + c.w;
  int scan = s;
#pragma unroll
  for (int m = 1; m < 64; m <<= 1) {
    int t = __shfl_up(scan, m, 64);
    if (lane >= m) scan += t;
  }
  int waveSum = __shfl(scan, 63, 64);
  int wbase = 0;
  if (lane == 63) wbase = atomicAdd(total, waveSum);
  wbase = __shfl(wbase, 63, 64);
  int ex = wbase + scan - s;
  if (i0 < n) {
    int b0 = ex, b1 = b0 + c.x, b2 = b1 + c.y, b3 = b2 + c.z;
    base[i0] = b0; cursor[i0] = b0;
    if (i0 + 1 < n) { base[i0 + 1] = b1; cursor[i0 + 1] = b1; }
    if (i0 + 2 < n) { base[i0 + 2] = b2; cursor[i0 + 2] = b2; }
    if (i0 + 3 < n) { base[i0 + 3] = b3; cursor[i0 + 3] = b3; }
  }
}

__global__ void k_bucket(const int* __restrict__ ei, const float* __restrict__ ew,
                         int* __restrict__ cursor, float2* __restrict__ srcPack, int ne) {
  int stride = gridDim.x * blockDim.x;
  for (int e = blockIdx.x * blockDim.x + threadIdx.x; e < ne; e += stride) {
    int r = ei[e], c = ei[ne + e];
    int p = atomicAdd(&cursor[c], 1);
    srcPack[p] = make_float2(__int_as_float(r), ew[e]);
  }
}

__global__ void k_deg(const float2* __restrict__ srcPack, const int* __restrict__ base,
                      const int* __restrict__ cnt, float* __restrict__ dinv, int n) {
  int lane = threadIdx.x & 63;
  int w = (blockIdx.x * blockDim.x + threadIdx.x) >> 6;
  int node = w * 4 + (lane >> 4);
  int sub = lane & 15;
  if (node >= n) return;
  int b = base[node], end = b + cnt[node];
  float s = 0.f;
  for (int e = b + sub; e < end; e += 16) s += srcPack[e].y;
#pragma unroll
  for (int m = 1; m < 16; m <<= 1) s += __shfl_xor(s, m, 64);
  if (sub == 0) dinv[node] = rsqrtf(1.0f + s);
}

// ---- LayerNorm (fp32 in, bf16 out) ----------------------------------------

__global__ void k_ln(const float* __restrict__ x, const float* __restrict__ lnw,
                     const float* __restrict__ lnb, __hip_bfloat162* __restrict__ xnB, int n) {
  int lane = threadIdx.x & 63;
  int row = blockIdx.x * 4 + (threadIdx.x >> 6);
  if (row >= n) return;
  float2 v = ((const float2*)(x + (size_t)row * DD))[lane];
  float s = v.x + v.y;
#pragma unroll
  for (int m = 32; m; m >>= 1) s += __shfl_xor(s, m, 64);
  float mu = s * 0.0078125f;
  float ex = v.x - mu, ey = v.y - mu;
  float q = ex * ex + ey * ey;
#pragma unroll
  for (int m = 32; m; m >>= 1) q += __shfl_xor(q, m, 64);
  float rstd = rsqrtf(q * 0.0078125f + LN_EPS_);
  float2 wv = ((const float2*)lnw)[lane];
  float2 bv = ((const float2*)lnb)[lane];
  xnB[(size_t)row * 64 + lane] =
      pack_bf162(ex * rstd * wv.x + bv.x, ey * rstd * wv.y + bv.y);
}

// ---- Gather-reduce aggregation (bf16 rows, fp32 accumulate) ----------------

__launch_bounds__(256)
__global__ void k_gather(const float2* __restrict__ srcPack, const int* __restrict__ base,
                         const int* __restrict__ cnt, const __hip_bfloat162* __restrict__ xnB,
                         const float* __restrict__ dinv, __hip_bfloat162* __restrict__ accB,
                         int n) {
  int lane = threadIdx.x & 63;
  int i = blockIdx.x * 4 + (threadIdx.x >> 6);
  if (i >= n) return;
  float di = dinv[i];
  float2 xi = __bfloat1622float2(xnB[(size_t)i * 64 + lane]);
  float2 s = make_float2(xi.x * di, xi.y * di);
  int b = base[i], end = b + cnt[i];
  for (int e0 = b; e0 < end; e0 += 64) {
    int m = min(64, end - e0);
    float2 p = make_float2(0.f, 0.f);
    if (lane < m) p = srcPack[e0 + lane];
    int src = __float_as_int(p.x);
    float ws = dinv[src] * p.y;
    int j = 0;
    for (; j + 1 < m; j += 2) {
      int s0 = __shfl(src, j, 64), s1 = __shfl(src, j + 1, 64);
      float w0 = __shfl(ws, j, 64), w1 = __shfl(ws, j + 1, 64);
      float2 v0 = __bfloat1622float2(xnB[(size_t)s0 * 64 + lane]);
      float2 v1 = __bfloat1622float2(xnB[(size_t)s1 * 64 + lane]);
      s.x = fmaf(v0.x, w0, s.x); s.y = fmaf(v0.y, w0, s.y);
      s.x = fmaf(v1.x, w1, s.x); s.y = fmaf(v1.y, w1, s.y);
    }
    if (j < m) {
      int s0 = __shfl(src, j, 64);
      float w0 = __shfl(ws, j, 64);
      float2 v0 = __bfloat1622float2(xnB[(size_t)s0 * 64 + lane]);
      s.x = fmaf(v0.x, w0, s.x); s.y = fmaf(v0.y, w0, s.y);
    }
  }
  accB[(size_t)i * 64 + lane] = pack_bf162(s.x * di, s.y * di);
}

// ---- W pre-pack into MFMA B-fragment order: [mat][ct][ks][lane][j] ---------
// B element (k, col): col = ct*16 + (lane&15), k = ks*32 + (lane>>4)*8 + j.

__global__ void k_pack_w(const float* __restrict__ Wg, const float* __restrict__ Wl,
                         __hip_bfloat16* __restrict__ pw) {
  int idx = blockIdx.x * blockDim.x + threadIdx.x;
  if (idx >= 2 * 16384) return;
  int j = idx & 7;
  int lane = (idx >> 3) & 63;
  int ks = (idx >> 9) & 3;
  int ct = (idx >> 11) & 7;
  int mat = idx >> 14;
  int col = ct * 16 + (lane & 15);
  int k = ks * 32 + (lane >> 4) * 8 + j;
  const float* W = mat ? Wl : Wg;
  pw[idx] = __float2bfloat16(W[k * DD + col]);
}

// ---- Fused final: out = leaky(acc@Wg + bg) + xn@Wl + bl  (MFMA, no LDS) ----
// One wave per 16-row panel. A-fragments read directly from row-major bf16
// global (16B contiguous per lane); B-fragments from pre-packed pw.

__launch_bounds__(256)
__global__ void k_final(const short* __restrict__ accB, const short* __restrict__ xnB,
                        const short* __restrict__ pw,
                        const float* __restrict__ bg, const float* __restrict__ bl,
                        float* __restrict__ out, int n) {
  int lane = threadIdx.x & 63;
  int panel = (blockIdx.x * blockDim.x + threadIdx.x) >> 6;
  int row0 = panel * 16;
  if (row0 >= n) return;
  int rlo = lane & 15, hi = lane >> 4;

  const short* arow = accB + (size_t)(row0 + rlo) * DD + hi * 8;
  const short* xrow = xnB + (size_t)(row0 + rlo) * DD + hi * 8;
  bf16x8 ag[4], al[4];
#pragma unroll
  for (int ks = 0; ks < 4; ++ks) {
    ag[ks] = *(const bf16x8*)(arow + ks * 32);
    al[ks] = *(const bf16x8*)(xrow + ks * 32);
  }

#pragma unroll
  for (int ct = 0; ct < 8; ++ct) {
    f32x4 cg = {0.f, 0.f, 0.f, 0.f}, cl = {0.f, 0.f, 0.f, 0.f};
#pragma unroll
    for (int ks = 0; ks < 4; ++ks) {
      bf16x8 bgf = *(const bf16x8*)(pw + ((size_t)(0 * 8 + ct) * 4 + ks) * 512 + lane * 8);
      bf16x8 blf = *(const bf16x8*)(pw + ((size_t)(1 * 8 + ct) * 4 + ks) * 512 + lane * 8);
      cg = __builtin_amdgcn_mfma_f32_16x16x32_bf16(ag[ks], bgf, cg, 0, 0, 0);
      cl = __builtin_amdgcn_mfma_f32_16x16x32_bf16(al[ks], blf, cl, 0, 0, 0);
    }
    int colg = ct * 16 + rlo;
    float bgv = bg[colg], blv = bl[colg];
#pragma unroll
    for (int r = 0; r < 4; ++r) {
      float g = cg[r] + bgv;
      g = (g >= 0.f) ? g : SLOPE * g;
      out[(size_t)(row0 + hi * 4 + r) * DD + colg] = g + cl[r] + blv;
    }
  }
}

extern "C" void kernel_launch(void* const* d_in, const int* in_sizes, int n_in,
                              void* d_out, int out_size, void* d_ws, size_t ws_size,
                              hipStream_t stream) {
  const float* x   = (const float*)d_in[0];
  const int*   ei  = (const int*)d_in[1];
  const float* ew  = (const float*)d_in[2];
  const float* lnw = (const float*)d_in[3];
  const float* lnb = (const float*)d_in[4];
  const float* Wg  = (const float*)d_in[5];
  const float* bg  = (const float*)d_in[6];
  const float* Wl  = (const float*)d_in[7];
  const float* bl  = (const float*)d_in[8];
  float* out = (float*)d_out;

  int n  = in_sizes[0] / DD;   // 50000
  int ne = in_sizes[1] / 2;    // 800000

  // workspace layout
  float2* srcPack = (float2*)d_ws;                            // ne * 8B
  __hip_bfloat162* xnB = (__hip_bfloat162*)(srcPack + ne);    // n*128 bf16 (12.8MB)
  __hip_bfloat162* accB = xnB + (size_t)n * 64;               // n*128 bf16 (12.8MB)
  __hip_bfloat16* pw = (__hip_bfloat16*)(accB + (size_t)n * 64);  // 32768 bf16 (64KB)
  float* dinv = (float*)(pw + 32768);                         // n
  int* cnt    = (int*)(dinv + n);                             // n
  int* base   = cnt + n;                                      // n
  int* cursor = base + n;                                     // n
  int* total  = cursor + n;                                   // 1

  int W = (n + 255) / 256;
  int offBlocks = (W * 64 + 255) / 256;

  k_init<<<(n + 255) / 256, 256, 0, stream>>>(cnt, total, n);
  k_count<<<1024, 256, 0, stream>>>(ei, cnt, ne);
  k_offsets<<<offBlocks, 256, 0, stream>>>(cnt, base, cursor, total, n);
  k_bucket<<<1024, 256, 0, stream>>>(ei, ew, cursor, srcPack, ne);
  k_ln<<<(n + 3) / 4, 256, 0, stream>>>(x, lnw, lnb, xnB, n);
  k_pack_w<<<128, 256, 0, stream>>>(Wg, Wl, pw);
  k_deg<<<(n + 15) / 16, 256, 0, stream>>>(srcPack, base, cnt, dinv, n);
  k_gather<<<(n + 3) / 4, 256, 0, stream>>>(srcPack, base, cnt, xnB, dinv, accB, n);

  int panels = (n + 15) / 16;
  int fBlocks = (panels * 64 + 255) / 256;
  k_final<<<fBlocks, 256, 0, stream>>>((const short*)accB, (const short*)xnB,
                                       (const short*)pw, bg, bl, out, n);
}

// Round 5
// 125.999 us; speedup vs baseline: 6.6451x; 1.3748x over previous
//
#include <hip/hip_runtime.h>
#include <hip/hip_bf16.h>

#define DD 128
#define LN_EPS_ 1e-5f
#define SLOPE 0.01f
#define SB 128           // nodes per coarse bucket
#define NB 391           // ceil(50000/128)

typedef __attribute__((ext_vector_type(8))) short bf16x8;
typedef __attribute__((ext_vector_type(4))) float f32x4;

__device__ __forceinline__ __hip_bfloat162 pack_bf162(float a, float b) {
  __hip_bfloat162 r;
  r.x = __float2bfloat16(a);
  r.y = __float2bfloat16(b);
  return r;
}

// ---- Phase A: coarse histogram (LDS, one flush atomic per bucket/block) ----

__launch_bounds__(256)
__global__ void k_hist(const int* __restrict__ eic, int* __restrict__ bhist, int ne) {
  __shared__ int lh[NB];
  int t = threadIdx.x;
  for (int i = t; i < NB; i += 256) lh[i] = 0;
  __syncthreads();
  int stride = gridDim.x * blockDim.x;
  for (int e = blockIdx.x * blockDim.x + t; e < ne; e += stride)
    atomicAdd(&lh[eic[e] >> 7], 1);
  __syncthreads();
  for (int i = t; i < NB; i += 256) {
    int v = lh[i];
    if (v) atomicAdd(&bhist[i], v);
  }
}

// ---- Phase B: scan bucket counts (1 block, 512 threads) --------------------

__launch_bounds__(512)
__global__ void k_scan(const int* __restrict__ bhist, int* __restrict__ bbase,
                       int* __restrict__ bcursor, int ne) {
  __shared__ int sc[2][512];
  int t = threadIdx.x;
  int v = (t < NB) ? bhist[t] : 0;
  sc[0][t] = v;
  __syncthreads();
  int pb = 0;
  for (int off = 1; off < 512; off <<= 1) {
    sc[pb ^ 1][t] = sc[pb][t] + (t >= off ? sc[pb][t - off] : 0);
    pb ^= 1;
    __syncthreads();
  }
  int inc = sc[pb][t];
  if (t < NB) {
    bbase[t] = inc - v;
    bcursor[t] = inc - v;
  }
  if (t == NB - 1) bbase[NB] = inc;  // == ne
}

// ---- Phase C: coarse scatter, block-chunked, semi-coalesced writes ---------
// packA[p] = (src | tl<<16, bits(ew)); tl = target within bucket.

__launch_bounds__(256)
__global__ void k_scatterA(const int* __restrict__ ei, const float* __restrict__ ew,
                           int* __restrict__ bcursor, uint2* __restrict__ packA, int ne) {
  __shared__ int lhist[NB];
  __shared__ int lbase[NB];
  int t = threadIdx.x;
  for (int i = t; i < NB; i += 256) lhist[i] = 0;
  __syncthreads();
  int per = (ne + gridDim.x - 1) / gridDim.x;
  int e0 = blockIdx.x * per, e1 = min(ne, e0 + per);
  for (int e = e0 + t; e < e1; e += 256) atomicAdd(&lhist[ei[ne + e] >> 7], 1);
  __syncthreads();
  for (int i = t; i < NB; i += 256) {
    int c = lhist[i];
    lbase[i] = c ? atomicAdd(&bcursor[i], c) : 0;
    lhist[i] = 0;  // becomes local cursor
  }
  __syncthreads();
  for (int e = e0 + t; e < e1; e += 256) {
    int c = ei[ne + e];
    int sb = c >> 7, tl = c & 127;
    int p = lbase[sb] + atomicAdd(&lhist[sb], 1);
    packA[p] = make_uint2((unsigned)ei[e] | ((unsigned)tl << 16), __float_as_uint(ew[e]));
  }
}

// ---- Phase D: per-bucket CSR build + degree + dinv (all LDS) ---------------

__launch_bounds__(256)
__global__ void k_csr(const uint2* __restrict__ packA, const int* __restrict__ bbase,
                      float2* __restrict__ packB, int* __restrict__ baseG,
                      int* __restrict__ cntG, float* __restrict__ dinv, int n) {
  __shared__ int cnt[SB];
  __shared__ float degl[SB];
  __shared__ int cur[SB];
  __shared__ int sc[2][SB];
  int b = blockIdx.x;
  int t = threadIdx.x;
  if (t < SB) { cnt[t] = 0; degl[t] = 0.f; }
  __syncthreads();
  int eb = bbase[b], ee = bbase[b + 1];
  for (int e = eb + t; e < ee; e += 256) {
    uint2 pk = packA[e];
    int tl = (pk.x >> 16) & 0xFF;
    atomicAdd(&cnt[tl], 1);
    atomicAdd(&degl[tl], __uint_as_float(pk.y));
  }
  __syncthreads();
  if (t < SB) sc[0][t] = cnt[t];
  __syncthreads();
  int pb = 0;
  for (int off = 1; off < SB; off <<= 1) {
    if (t < SB) sc[pb ^ 1][t] = sc[pb][t] + (t >= off ? sc[pb][t - off] : 0);
    pb ^= 1;
    __syncthreads();
  }
  if (t < SB) {
    int node = b * SB + t;
    if (node < n) {
      int inc = sc[pb][t];
      int ex = inc - cnt[t];
      dinv[node] = rsqrtf(1.0f + degl[t]);
      baseG[node] = eb + ex;
      cntG[node] = cnt[t];
      cur[t] = ex;
    }
  }
  __syncthreads();
  for (int e = eb + t; e < ee; e += 256) {
    uint2 pk = packA[e];
    int tl = (pk.x >> 16) & 0xFF;
    int p = atomicAdd(&cur[tl], 1);
    packB[eb + p] = make_float2(__int_as_float((int)(pk.x & 0xFFFFu)), __uint_as_float(pk.y));
  }
}

// ---- LayerNorm (fp32 in, bf16 out) ----------------------------------------

__global__ void k_ln(const float* __restrict__ x, const float* __restrict__ lnw,
                     const float* __restrict__ lnb, __hip_bfloat162* __restrict__ xnB, int n) {
  int lane = threadIdx.x & 63;
  int row = blockIdx.x * 4 + (threadIdx.x >> 6);
  if (row >= n) return;
  float2 v = ((const float2*)(x + (size_t)row * DD))[lane];
  float s = v.x + v.y;
#pragma unroll
  for (int m = 32; m; m >>= 1) s += __shfl_xor(s, m, 64);
  float mu = s * 0.0078125f;
  float ex = v.x - mu, ey = v.y - mu;
  float q = ex * ex + ey * ey;
#pragma unroll
  for (int m = 32; m; m >>= 1) q += __shfl_xor(q, m, 64);
  float rstd = rsqrtf(q * 0.0078125f + LN_EPS_);
  float2 wv = ((const float2*)lnw)[lane];
  float2 bv = ((const float2*)lnb)[lane];
  xnB[(size_t)row * 64 + lane] =
      pack_bf162(ex * rstd * wv.x + bv.x, ey * rstd * wv.y + bv.y);
}

// ---- Gather-reduce aggregation (bf16 rows, fp32 accumulate) ----------------

__launch_bounds__(256)
__global__ void k_gather(const float2* __restrict__ srcPack, const int* __restrict__ base,
                         const int* __restrict__ cnt, const __hip_bfloat162* __restrict__ xnB,
                         const float* __restrict__ dinv, __hip_bfloat162* __restrict__ accB,
                         int n) {
  int lane = threadIdx.x & 63;
  int i = blockIdx.x * 4 + (threadIdx.x >> 6);
  if (i >= n) return;
  float di = dinv[i];
  float2 xi = __bfloat1622float2(xnB[(size_t)i * 64 + lane]);
  float2 s = make_float2(xi.x * di, xi.y * di);
  int b = base[i], end = b + cnt[i];
  for (int e0 = b; e0 < end; e0 += 64) {
    int m = min(64, end - e0);
    float2 p = make_float2(0.f, 0.f);
    if (lane < m) p = srcPack[e0 + lane];
    int src = __float_as_int(p.x);
    float ws = dinv[src] * p.y;
    int j = 0;
    for (; j + 1 < m; j += 2) {
      int s0 = __shfl(src, j, 64), s1 = __shfl(src, j + 1, 64);
      float w0 = __shfl(ws, j, 64), w1 = __shfl(ws, j + 1, 64);
      float2 v0 = __bfloat1622float2(xnB[(size_t)s0 * 64 + lane]);
      float2 v1 = __bfloat1622float2(xnB[(size_t)s1 * 64 + lane]);
      s.x = fmaf(v0.x, w0, s.x); s.y = fmaf(v0.y, w0, s.y);
      s.x = fmaf(v1.x, w1, s.x); s.y = fmaf(v1.y, w1, s.y);
    }
    if (j < m) {
      int s0 = __shfl(src, j, 64);
      float w0 = __shfl(ws, j, 64);
      float2 v0 = __bfloat1622float2(xnB[(size_t)s0 * 64 + lane]);
      s.x = fmaf(v0.x, w0, s.x); s.y = fmaf(v0.y, w0, s.y);
    }
  }
  accB[(size_t)i * 64 + lane] = pack_bf162(s.x * di, s.y * di);
}

// ---- W pre-pack into MFMA B-fragment order: [mat][ct][ks][lane][j] ---------

__global__ void k_pack_w(const float* __restrict__ Wg, const float* __restrict__ Wl,
                         __hip_bfloat16* __restrict__ pw) {
  int idx = blockIdx.x * blockDim.x + threadIdx.x;
  if (idx >= 2 * 16384) return;
  int j = idx & 7;
  int lane = (idx >> 3) & 63;
  int ks = (idx >> 9) & 3;
  int ct = (idx >> 11) & 7;
  int mat = idx >> 14;
  int col = ct * 16 + (lane & 15);
  int k = ks * 32 + (lane >> 4) * 8 + j;
  const float* W = mat ? Wl : Wg;
  pw[idx] = __float2bfloat16(W[k * DD + col]);
}

// ---- Fused final: out = leaky(acc@Wg + bg) + xn@Wl + bl  (MFMA, no LDS) ----

__launch_bounds__(256)
__global__ void k_final(const short* __restrict__ accB, const short* __restrict__ xnB,
                        const short* __restrict__ pw,
                        const float* __restrict__ bg, const float* __restrict__ bl,
                        float* __restrict__ out, int n) {
  int lane = threadIdx.x & 63;
  int panel = (blockIdx.x * blockDim.x + threadIdx.x) >> 6;
  int row0 = panel * 16;
  if (row0 >= n) return;
  int rlo = lane & 15, hi = lane >> 4;

  const short* arow = accB + (size_t)(row0 + rlo) * DD + hi * 8;
  const short* xrow = xnB + (size_t)(row0 + rlo) * DD + hi * 8;
  bf16x8 ag[4], al[4];
#pragma unroll
  for (int ks = 0; ks < 4; ++ks) {
    ag[ks] = *(const bf16x8*)(arow + ks * 32);
    al[ks] = *(const bf16x8*)(xrow + ks * 32);
  }

#pragma unroll
  for (int ct = 0; ct < 8; ++ct) {
    f32x4 cg = {0.f, 0.f, 0.f, 0.f}, cl = {0.f, 0.f, 0.f, 0.f};
#pragma unroll
    for (int ks = 0; ks < 4; ++ks) {
      bf16x8 bgf = *(const bf16x8*)(pw + ((size_t)(0 * 8 + ct) * 4 + ks) * 512 + lane * 8);
      bf16x8 blf = *(const bf16x8*)(pw + ((size_t)(1 * 8 + ct) * 4 + ks) * 512 + lane * 8);
      cg = __builtin_amdgcn_mfma_f32_16x16x32_bf16(ag[ks], bgf, cg, 0, 0, 0);
      cl = __builtin_amdgcn_mfma_f32_16x16x32_bf16(al[ks], blf, cl, 0, 0, 0);
    }
    int colg = ct * 16 + rlo;
    float bgv = bg[colg], blv = bl[colg];
#pragma unroll
    for (int r = 0; r < 4; ++r) {
      float g = cg[r] + bgv;
      g = (g >= 0.f) ? g : SLOPE * g;
      out[(size_t)(row0 + hi * 4 + r) * DD + colg] = g + cl[r] + blv;
    }
  }
}

extern "C" void kernel_launch(void* const* d_in, const int* in_sizes, int n_in,
                              void* d_out, int out_size, void* d_ws, size_t ws_size,
                              hipStream_t stream) {
  const float* x   = (const float*)d_in[0];
  const int*   ei  = (const int*)d_in[1];
  const float* ew  = (const float*)d_in[2];
  const float* lnw = (const float*)d_in[3];
  const float* lnb = (const float*)d_in[4];
  const float* Wg  = (const float*)d_in[5];
  const float* bg  = (const float*)d_in[6];
  const float* Wl  = (const float*)d_in[7];
  const float* bl  = (const float*)d_in[8];
  float* out = (float*)d_out;

  int n  = in_sizes[0] / DD;   // 50000 (fits u16 packing: n < 65536)
  int ne = in_sizes[1] / 2;    // 800000

  // workspace layout
  uint2* packA = (uint2*)d_ws;                                // ne*8B
  float2* packB = (float2*)(packA + ne);                      // ne*8B
  __hip_bfloat162* xnB = (__hip_bfloat162*)(packB + ne);      // n*128 bf16
  __hip_bfloat162* accB = xnB + (size_t)n * 64;               // n*128 bf16
  __hip_bfloat16* pw = (__hip_bfloat16*)(accB + (size_t)n * 64);  // 32768 bf16
  float* dinv = (float*)(pw + 32768);                         // n
  int* base   = (int*)(dinv + n);                             // n
  int* cnt    = base + n;                                     // n
  int* bhist  = cnt + n;                                      // NB
  int* bbase  = bhist + NB;                                   // NB+1
  int* bcursor= bbase + NB + 1;                               // NB

  hipMemsetAsync(bhist, 0, NB * sizeof(int), stream);
  k_hist<<<256, 256, 0, stream>>>(ei + ne, bhist, ne);
  k_scan<<<1, 512, 0, stream>>>(bhist, bbase, bcursor, ne);
  k_scatterA<<<200, 256, 0, stream>>>(ei, ew, bcursor, packA, ne);
  k_csr<<<NB, 256, 0, stream>>>(packA, bbase, packB, base, cnt, dinv, n);
  k_ln<<<(n + 3) / 4, 256, 0, stream>>>(x, lnw, lnb, xnB, n);
  k_pack_w<<<128, 256, 0, stream>>>(Wg, Wl, pw);
  k_gather<<<(n + 3) / 4, 256, 0, stream>>>(packB, base, cnt, xnB, dinv, accB, n);

  int panels = (n + 15) / 16;
  int fBlocks = (panels * 64 + 255) / 256;
  k_final<<<fBlocks, 256, 0, stream>>>((const short*)accB, (const short*)xnB,
                                       (const short*)pw, bg, bl, out, n);
}

// Round 6
// 114.787 us; speedup vs baseline: 7.2942x; 1.0977x over previous
//
#include <hip/hip_runtime.h>
#include <hip/hip_bf16.h>

#define DD 128
#define LN_EPS_ 1e-5f
#define SLOPE 0.01f
#define SB 128           // nodes per coarse bucket
#define NB 391           // ceil(50000/128)
#define HB 256           // histogram blocks
#define LNB 12500        // LN blocks (4 rows each)

typedef __attribute__((ext_vector_type(8))) short bf16x8;
typedef __attribute__((ext_vector_type(4))) float f32x4;

__device__ __forceinline__ __hip_bfloat162 pack_bf162(float a, float b) {
  __hip_bfloat162 r;
  r.x = __float2bfloat16(a);
  r.y = __float2bfloat16(b);
  return r;
}

// ---- Fused prep: partial histograms (blocks 0..255) | LayerNorm | pack_w ---

__launch_bounds__(256)
__global__ void k_big1(const int* __restrict__ eic, int* __restrict__ bhistT,
                       const float* __restrict__ x, const float* __restrict__ lnw,
                       const float* __restrict__ lnb, __hip_bfloat162* __restrict__ xnB,
                       const float* __restrict__ Wg, const float* __restrict__ Wl,
                       __hip_bfloat16* __restrict__ pw, int ne, int n) {
  __shared__ int lh[NB];
  int bid = blockIdx.x;
  int t = threadIdx.x;
  if (bid < HB) {
    // partial histogram: no global atomics, no zero-init needed
    for (int i = t; i < NB; i += 256) lh[i] = 0;
    __syncthreads();
    for (int e = bid * 256 + t; e < ne; e += HB * 256) atomicAdd(&lh[eic[e] >> 7], 1);
    __syncthreads();
    for (int i = t; i < NB; i += 256) bhistT[i * HB + bid] = lh[i];  // transposed
  } else if (bid < HB + LNB) {
    int lane = t & 63;
    int row = (bid - HB) * 4 + (t >> 6);
    if (row >= n) return;
    float2 v = ((const float2*)(x + (size_t)row * DD))[lane];
    float s = v.x + v.y;
#pragma unroll
    for (int m = 32; m; m >>= 1) s += __shfl_xor(s, m, 64);
    float mu = s * 0.0078125f;
    float ex = v.x - mu, ey = v.y - mu;
    float q = ex * ex + ey * ey;
#pragma unroll
    for (int m = 32; m; m >>= 1) q += __shfl_xor(q, m, 64);
    float rstd = rsqrtf(q * 0.0078125f + LN_EPS_);
    float2 wv = ((const float2*)lnw)[lane];
    float2 bv = ((const float2*)lnb)[lane];
    xnB[(size_t)row * 64 + lane] =
        pack_bf162(ex * rstd * wv.x + bv.x, ey * rstd * wv.y + bv.y);
  } else {
    int idx = (bid - HB - LNB) * 256 + t;
    if (idx >= 2 * 16384) return;
    int j = idx & 7;
    int lane = (idx >> 3) & 63;
    int ks = (idx >> 9) & 3;
    int ct = (idx >> 11) & 7;
    int mat = idx >> 14;
    int col = ct * 16 + (lane & 15);
    int k = ks * 32 + (lane >> 4) * 8 + j;
    const float* W = mat ? Wl : Wg;
    pw[idx] = __float2bfloat16(W[k * DD + col]);
  }
}

// ---- Scan bucket totals (1 block) ------------------------------------------

__launch_bounds__(512)
__global__ void k_scan(const int* __restrict__ bhistT, int* __restrict__ bbase,
                       int* __restrict__ bcursor, int ne) {
  __shared__ int sc[2][512];
  int t = threadIdx.x;
  int v = 0;
  if (t < NB) {
    const int4* col = (const int4*)(bhistT + t * HB);
    for (int b = 0; b < HB / 4; ++b) {
      int4 c = col[b];
      v += c.x + c.y + c.z + c.w;
    }
  }
  sc[0][t] = v;
  __syncthreads();
  int pb = 0;
  for (int off = 1; off < 512; off <<= 1) {
    sc[pb ^ 1][t] = sc[pb][t] + (t >= off ? sc[pb][t - off] : 0);
    pb ^= 1;
    __syncthreads();
  }
  int inc = sc[pb][t];
  if (t < NB) {
    bbase[t] = inc - v;
    bcursor[t] = inc - v;
  }
  if (t == NB - 1) bbase[NB] = inc;  // == ne
}

// ---- Coarse scatter --------------------------------------------------------

__launch_bounds__(256)
__global__ void k_scatterA(const int* __restrict__ ei, const float* __restrict__ ew,
                           int* __restrict__ bcursor, uint2* __restrict__ packA, int ne) {
  __shared__ int lhist[NB];
  __shared__ int lbase[NB];
  int t = threadIdx.x;
  for (int i = t; i < NB; i += 256) lhist[i] = 0;
  __syncthreads();
  int per = (ne + gridDim.x - 1) / gridDim.x;
  int e0 = blockIdx.x * per, e1 = min(ne, e0 + per);
  for (int e = e0 + t; e < e1; e += 256) atomicAdd(&lhist[ei[ne + e] >> 7], 1);
  __syncthreads();
  for (int i = t; i < NB; i += 256) {
    int c = lhist[i];
    lbase[i] = c ? atomicAdd(&bcursor[i], c) : 0;
    lhist[i] = 0;  // becomes local cursor
  }
  __syncthreads();
  for (int e = e0 + t; e < e1; e += 256) {
    int c = ei[ne + e];
    int sb = c >> 7, tl = c & 127;
    int p = lbase[sb] + atomicAdd(&lhist[sb], 1);
    packA[p] = make_uint2((unsigned)ei[e] | ((unsigned)tl << 16), __float_as_uint(ew[e]));
  }
}

// ---- Per-bucket CSR build + degree + dinv ----------------------------------

__launch_bounds__(256)
__global__ void k_csr(const uint2* __restrict__ packA, const int* __restrict__ bbase,
                      float2* __restrict__ packB, int* __restrict__ baseG,
                      int* __restrict__ cntG, float* __restrict__ dinv, int n) {
  __shared__ int cnt[SB];
  __shared__ float degl[SB];
  __shared__ int cur[SB];
  __shared__ int sc[2][SB];
  int b = blockIdx.x;
  int t = threadIdx.x;
  if (t < SB) { cnt[t] = 0; degl[t] = 0.f; }
  __syncthreads();
  int eb = bbase[b], ee = bbase[b + 1];
  for (int e = eb + t; e < ee; e += 256) {
    uint2 pk = packA[e];
    int tl = (pk.x >> 16) & 0xFF;
    atomicAdd(&cnt[tl], 1);
    atomicAdd(&degl[tl], __uint_as_float(pk.y));
  }
  __syncthreads();
  if (t < SB) sc[0][t] = cnt[t];
  __syncthreads();
  int pb = 0;
  for (int off = 1; off < SB; off <<= 1) {
    if (t < SB) sc[pb ^ 1][t] = sc[pb][t] + (t >= off ? sc[pb][t - off] : 0);
    pb ^= 1;
    __syncthreads();
  }
  if (t < SB) {
    int node = b * SB + t;
    if (node < n) {
      int inc = sc[pb][t];
      int ex = inc - cnt[t];
      dinv[node] = rsqrtf(1.0f + degl[t]);
      baseG[node] = eb + ex;
      cntG[node] = cnt[t];
      cur[t] = ex;
    }
  }
  __syncthreads();
  for (int e = eb + t; e < ee; e += 256) {
    uint2 pk = packA[e];
    int tl = (pk.x >> 16) & 0xFF;
    int p = atomicAdd(&cur[tl], 1);
    packB[eb + p] = make_float2(__int_as_float((int)(pk.x & 0xFFFFu)), __uint_as_float(pk.y));
  }
}

// ---- Fused gather + MFMA final ---------------------------------------------
// Block = 256 threads (4 waves) handles 16 nodes. Phase 1: wave w gathers
// nodes w*4..w*4+3 into LDS tile (bf16, 272B row stride). Phase 2: wave w
// computes col-tiles {2w, 2w+1} of out = leaky(agg@Wg+bg) + xn@Wl + bl.

__launch_bounds__(256)
__global__ void k_gf(const float2* __restrict__ packB, const int* __restrict__ base,
                     const int* __restrict__ cnt, const __hip_bfloat162* __restrict__ xnB,
                     const float* __restrict__ dinv, const short* __restrict__ pw,
                     const float* __restrict__ bg, const float* __restrict__ bl,
                     float* __restrict__ out, int n) {
  __shared__ short tile[16][136];  // 272B stride: 16B-aligned, bank-spread
  int t = threadIdx.x;
  int lane = t & 63, w = t >> 6;
  int row0 = blockIdx.x * 16;

  for (int sub = 0; sub < 4; ++sub) {
    int r = w * 4 + sub;
    int i = row0 + r;
    float2 s = make_float2(0.f, 0.f);
    if (i < n) {
      float di = dinv[i];
      float2 xi = __bfloat1622float2(xnB[(size_t)i * 64 + lane]);
      s = make_float2(xi.x * di, xi.y * di);
      int b = base[i], end = b + cnt[i];
      for (int e0 = b; e0 < end; e0 += 64) {
        int m = min(64, end - e0);
        float2 p = make_float2(0.f, 0.f);
        if (lane < m) p = packB[e0 + lane];
        int src = __float_as_int(p.x);
        float ws = dinv[src] * p.y;
        int j = 0;
        for (; j + 3 < m; j += 4) {
          int s0 = __shfl(src, j, 64), s1 = __shfl(src, j + 1, 64);
          int s2 = __shfl(src, j + 2, 64), s3 = __shfl(src, j + 3, 64);
          float w0 = __shfl(ws, j, 64), w1 = __shfl(ws, j + 1, 64);
          float w2 = __shfl(ws, j + 2, 64), w3 = __shfl(ws, j + 3, 64);
          float2 v0 = __bfloat1622float2(xnB[(size_t)s0 * 64 + lane]);
          float2 v1 = __bfloat1622float2(xnB[(size_t)s1 * 64 + lane]);
          float2 v2 = __bfloat1622float2(xnB[(size_t)s2 * 64 + lane]);
          float2 v3 = __bfloat1622float2(xnB[(size_t)s3 * 64 + lane]);
          s.x = fmaf(v0.x, w0, s.x); s.y = fmaf(v0.y, w0, s.y);
          s.x = fmaf(v1.x, w1, s.x); s.y = fmaf(v1.y, w1, s.y);
          s.x = fmaf(v2.x, w2, s.x); s.y = fmaf(v2.y, w2, s.y);
          s.x = fmaf(v3.x, w3, s.x); s.y = fmaf(v3.y, w3, s.y);
        }
        for (; j < m; ++j) {
          int s0 = __shfl(src, j, 64);
          float w0 = __shfl(ws, j, 64);
          float2 v0 = __bfloat1622float2(xnB[(size_t)s0 * 64 + lane]);
          s.x = fmaf(v0.x, w0, s.x); s.y = fmaf(v0.y, w0, s.y);
        }
      }
      s.x *= di; s.y *= di;
    }
    *(__hip_bfloat162*)&tile[r][lane * 2] = pack_bf162(s.x, s.y);
  }
  __syncthreads();

  // Phase 2: MFMA. A-frag from LDS tile; residual A from global xnB.
  int rlo = lane & 15, hi = lane >> 4;
  int arow = row0 + rlo < n ? row0 + rlo : n - 1;
  const short* trow = &tile[rlo][hi * 8];
  const short* xrow = (const short*)xnB + (size_t)arow * DD + hi * 8;
  bf16x8 ag[4], al[4];
#pragma unroll
  for (int ks = 0; ks < 4; ++ks) {
    ag[ks] = *(const bf16x8*)(trow + ks * 32);
    al[ks] = *(const bf16x8*)(xrow + ks * 32);
  }

#pragma unroll
  for (int cc = 0; cc < 2; ++cc) {
    int ct = w * 2 + cc;
    f32x4 cg = {0.f, 0.f, 0.f, 0.f}, cl = {0.f, 0.f, 0.f, 0.f};
#pragma unroll
    for (int ks = 0; ks < 4; ++ks) {
      bf16x8 bgf = *(const bf16x8*)(pw + ((size_t)(0 * 8 + ct) * 4 + ks) * 512 + lane * 8);
      bf16x8 blf = *(const bf16x8*)(pw + ((size_t)(1 * 8 + ct) * 4 + ks) * 512 + lane * 8);
      cg = __builtin_amdgcn_mfma_f32_16x16x32_bf16(ag[ks], bgf, cg, 0, 0, 0);
      cl = __builtin_amdgcn_mfma_f32_16x16x32_bf16(al[ks], blf, cl, 0, 0, 0);
    }
    int colg = ct * 16 + rlo;
    float bgv = bg[colg], blv = bl[colg];
#pragma unroll
    for (int r = 0; r < 4; ++r) {
      int row = row0 + hi * 4 + r;
      if (row < n) {
        float g = cg[r] + bgv;
        g = (g >= 0.f) ? g : SLOPE * g;
        out[(size_t)row * DD + colg] = g + cl[r] + blv;
      }
    }
  }
}

extern "C" void kernel_launch(void* const* d_in, const int* in_sizes, int n_in,
                              void* d_out, int out_size, void* d_ws, size_t ws_size,
                              hipStream_t stream) {
  const float* x   = (const float*)d_in[0];
  const int*   ei  = (const int*)d_in[1];
  const float* ew  = (const float*)d_in[2];
  const float* lnw = (const float*)d_in[3];
  const float* lnb = (const float*)d_in[4];
  const float* Wg  = (const float*)d_in[5];
  const float* bg  = (const float*)d_in[6];
  const float* Wl  = (const float*)d_in[7];
  const float* bl  = (const float*)d_in[8];
  float* out = (float*)d_out;

  int n  = in_sizes[0] / DD;   // 50000
  int ne = in_sizes[1] / 2;    // 800000

  // workspace layout
  uint2* packA = (uint2*)d_ws;                                // ne*8B
  float2* packB = (float2*)(packA + ne);                      // ne*8B
  __hip_bfloat162* xnB = (__hip_bfloat162*)(packB + ne);      // n*128 bf16
  __hip_bfloat16* pw = (__hip_bfloat16*)(xnB + (size_t)n * 64);  // 32768 bf16
  float* dinv = (float*)(pw + 32768);                         // n
  int* base   = (int*)(dinv + n);                             // n
  int* cnt    = base + n;                                     // n
  int* bhistT = cnt + n;                                      // NB*HB (transposed)
  int* bbase  = bhistT + NB * HB;                             // NB+1
  int* bcursor= bbase + NB + 1;                               // NB

  int packBlocks = (2 * 16384 + 255) / 256;  // 128
  k_big1<<<HB + LNB + packBlocks, 256, 0, stream>>>(ei + ne, bhistT, x, lnw, lnb,
                                                    xnB, Wg, Wl, pw, ne, n);
  k_scan<<<1, 512, 0, stream>>>(bhistT, bbase, bcursor, ne);
  k_scatterA<<<200, 256, 0, stream>>>(ei, ew, bcursor, packA, ne);
  k_csr<<<NB, 256, 0, stream>>>(packA, bbase, packB, base, cnt, dinv, n);
  k_gf<<<(n + 15) / 16, 256, 0, stream>>>(packB, base, cnt, xnB, dinv,
                                          (const short*)pw, bg, bl, out, n);
}